// Round 1
// baseline (432.085 us; speedup 1.0000x reference)
//
#include <hip/hip_runtime.h>
#include <math.h>

#define N_NODES 10000
#define N_EDGES 320000
#define N_AUG   (N_EDGES + N_NODES)
#define HID     256

// ---------------- degree + edge_attr segment sum ----------------
__global__ void k_deg(const int* __restrict__ dst, const float* __restrict__ ea,
                      int* __restrict__ deg, float* __restrict__ asum) {
  int e = blockIdx.x * blockDim.x + threadIdx.x;
  if (e < N_EDGES) {
    int d = dst[e];
    atomicAdd(&deg[d], 1);
    atomicAdd(&asum[d], ea[e]);
  }
}

// ---------------- exclusive scan of (deg+1) over 10000 nodes, + loop_attr ----
__global__ void k_scan(const int* __restrict__ deg, const float* __restrict__ asum,
                       int* __restrict__ offs, float* __restrict__ lattr) {
  __shared__ int part[256];
  __shared__ int excl[257];
  int t = threadIdx.x;
  int base = t * 40;
  int s = 0;
  for (int i = 0; i < 40; i++) {
    int n = base + i;
    if (n < N_NODES) s += deg[n] + 1;
  }
  part[t] = s;
  __syncthreads();
  if (t == 0) {
    int run = 0;
    for (int i = 0; i < 256; i++) { excl[i] = run; run += part[i]; }
    excl[256] = run;
  }
  __syncthreads();
  int run = excl[t];
  for (int i = 0; i < 40; i++) {
    int n = base + i;
    if (n < N_NODES) {
      offs[n] = run;
      int d = deg[n];
      run += d + 1;
      lattr[n] = asum[n] / (float)max(d, 1);
    }
  }
  if (t == 0) offs[N_NODES] = excl[256];
}

// ---------------- scatter edges (incl. self loops) into CSR by dst ----------
__global__ void k_scatter(const int* __restrict__ src, const int* __restrict__ dst,
                          const float* __restrict__ ea, const float* __restrict__ lattr,
                          const int* __restrict__ offs, int* __restrict__ cursor,
                          int* __restrict__ csrc, float* __restrict__ cea) {
  int e = blockIdx.x * blockDim.x + threadIdx.x;
  if (e >= N_AUG) return;
  int s, d; float a;
  if (e < N_EDGES) { s = src[e]; d = dst[e]; a = ea[e]; }
  else             { s = e - N_EDGES; d = s; a = lattr[s]; }
  int pos = offs[d] + atomicAdd(&cursor[d], 1);
  csrc[pos] = s;
  cea[pos]  = a;
}

// ---------------- conv1 node transform: x(N,4) @ W(4,256) + b  (xl and xr) --
__global__ void __launch_bounds__(64) k_xform1(
    const float* __restrict__ x,
    const float* __restrict__ Wl, const float* __restrict__ bl,
    const float* __restrict__ Wr, const float* __restrict__ br,
    float* __restrict__ xl, float* __restrict__ xr) {
  int n = blockIdx.x;
  int c = 4 * threadIdx.x;
  float x0 = x[n*4+0], x1 = x[n*4+1], x2 = x[n*4+2], x3 = x[n*4+3];

  float4 w0 = *(const float4*)&Wl[0*HID + c];
  float4 w1 = *(const float4*)&Wl[1*HID + c];
  float4 w2 = *(const float4*)&Wl[2*HID + c];
  float4 w3 = *(const float4*)&Wl[3*HID + c];
  float4 b  = *(const float4*)&bl[c];
  float4 o;
  o.x = fmaf(x0,w0.x, fmaf(x1,w1.x, fmaf(x2,w2.x, fmaf(x3,w3.x, b.x))));
  o.y = fmaf(x0,w0.y, fmaf(x1,w1.y, fmaf(x2,w2.y, fmaf(x3,w3.y, b.y))));
  o.z = fmaf(x0,w0.z, fmaf(x1,w1.z, fmaf(x2,w2.z, fmaf(x3,w3.z, b.z))));
  o.w = fmaf(x0,w0.w, fmaf(x1,w1.w, fmaf(x2,w2.w, fmaf(x3,w3.w, b.w))));
  *(float4*)&xl[n*HID + c] = o;

  w0 = *(const float4*)&Wr[0*HID + c];
  w1 = *(const float4*)&Wr[1*HID + c];
  w2 = *(const float4*)&Wr[2*HID + c];
  w3 = *(const float4*)&Wr[3*HID + c];
  b  = *(const float4*)&br[c];
  o.x = fmaf(x0,w0.x, fmaf(x1,w1.x, fmaf(x2,w2.x, fmaf(x3,w3.x, b.x))));
  o.y = fmaf(x0,w0.y, fmaf(x1,w1.y, fmaf(x2,w2.y, fmaf(x3,w3.y, b.y))));
  o.z = fmaf(x0,w0.z, fmaf(x1,w1.z, fmaf(x2,w2.z, fmaf(x3,w3.z, b.z))));
  o.w = fmaf(x0,w0.w, fmaf(x1,w1.w, fmaf(x2,w2.w, fmaf(x3,w3.w, b.w))));
  *(float4*)&xr[n*HID + c] = o;
}

// ---------------- fused GATv2 aggregation + bias + LayerNorm + ReLU ---------
// One wave (64 lanes) per dst node; lane l owns channels 4l..4l+3.
// WRED = head width in lanes*? : 16 -> 4 heads of 64 ch, 64 -> 1 head of 256 ch.
template<int WRED>
__global__ void __launch_bounds__(64) k_conv(
    const float* __restrict__ xl, const float* __restrict__ xr,
    const int* __restrict__ offs, const int* __restrict__ csrc,
    const float* __restrict__ cea,
    const float* __restrict__ We, const float* __restrict__ att,
    const float* __restrict__ bias, const float* __restrict__ g,
    const float* __restrict__ be, float* __restrict__ hout) {
  int n = blockIdx.x;
  int c = 4 * threadIdx.x;
  float4 r4 = *(const float4*)&xr[n*HID + c];
  float4 we = *(const float4*)&We[c];
  float4 at = *(const float4*)&att[c];
  int js = offs[n], je = offs[n+1];

  float M = -1e30f, D = 0.f;
  float a0 = 0.f, a1 = 0.f, a2 = 0.f, a3 = 0.f;

  for (int j = js; j < je; j++) {
    int s  = csrc[j];
    float a = cea[j];
    float4 xs = *(const float4*)&xl[s*HID + c];
    float m0 = xs.x + r4.x + a*we.x; m0 = m0 > 0.f ? m0 : 0.2f*m0;
    float m1 = xs.y + r4.y + a*we.y; m1 = m1 > 0.f ? m1 : 0.2f*m1;
    float m2 = xs.z + r4.z + a*we.z; m2 = m2 > 0.f ? m2 : 0.2f*m2;
    float m3 = xs.w + r4.w + a*we.w; m3 = m3 > 0.f ? m3 : 0.2f*m3;
    float p = m0*at.x + m1*at.y + m2*at.z + m3*at.w;
    #pragma unroll
    for (int msk = 1; msk < WRED; msk <<= 1) p += __shfl_xor(p, msk);
    if (p > M) {
      float sc = expf(M - p);
      D *= sc; a0 *= sc; a1 *= sc; a2 *= sc; a3 *= sc;
      M = p;
    }
    float ex = expf(p - M);
    D += ex;
    a0 = fmaf(ex, xs.x, a0);
    a1 = fmaf(ex, xs.y, a1);
    a2 = fmaf(ex, xs.z, a2);
    a3 = fmaf(ex, xs.w, a3);
  }

  float inv = 1.f / D;
  float4 b4 = *(const float4*)&bias[c];
  float o0 = fmaf(a0, inv, b4.x);
  float o1 = fmaf(a1, inv, b4.y);
  float o2 = fmaf(a2, inv, b4.z);
  float o3 = fmaf(a3, inv, b4.w);

  // LayerNorm over 256 channels (whole wave) + affine + ReLU
  float s = o0 + o1 + o2 + o3;
  #pragma unroll
  for (int msk = 1; msk < 64; msk <<= 1) s += __shfl_xor(s, msk);
  float mu = s * (1.f / 256.f);
  float d0 = o0 - mu, d1 = o1 - mu, d2 = o2 - mu, d3 = o3 - mu;
  float sq = d0*d0 + d1*d1 + d2*d2 + d3*d3;
  #pragma unroll
  for (int msk = 1; msk < 64; msk <<= 1) sq += __shfl_xor(sq, msk);
  float rstd = rsqrtf(sq * (1.f / 256.f) + 1e-5f);
  float4 g4  = *(const float4*)&g[c];
  float4 be4 = *(const float4*)&be[c];
  float4 o;
  o.x = fmaxf(fmaf(d0 * rstd, g4.x, be4.x), 0.f);
  o.y = fmaxf(fmaf(d1 * rstd, g4.y, be4.y), 0.f);
  o.z = fmaxf(fmaf(d2 * rstd, g4.z, be4.z), 0.f);
  o.w = fmaxf(fmaf(d3 * rstd, g4.w, be4.w), 0.f);
  *(float4*)&hout[n*HID + c] = o;
}

// ---------------- dual GEMM: O1 = A@W1+b1, O2 = A@W2+b2  (A: 10000x256) -----
__global__ void __launch_bounds__(256) k_gemm_dual(
    const float* __restrict__ A,
    const float* __restrict__ W1, const float* __restrict__ b1,
    const float* __restrict__ W2, const float* __restrict__ b2,
    float* __restrict__ O1, float* __restrict__ O2) {
  __shared__ float As[16][HID];
  int t = threadIdx.x;
  int r0 = blockIdx.x * 16;
  for (int i = 0; i < 16; i++) As[i][t] = A[(r0 + i) * HID + t];
  __syncthreads();
  float acc1[16], acc2[16];
  float bb1 = b1[t], bb2 = b2[t];
  #pragma unroll
  for (int r = 0; r < 16; r++) { acc1[r] = bb1; acc2[r] = bb2; }
  for (int k = 0; k < HID; k++) {
    float w1 = W1[k*HID + t];
    float w2 = W2[k*HID + t];
    #pragma unroll
    for (int r = 0; r < 16; r++) {
      float av = As[r][k];
      acc1[r] = fmaf(av, w1, acc1[r]);
      acc2[r] = fmaf(av, w2, acc2[r]);
    }
  }
  for (int r = 0; r < 16; r++) {
    O1[(r0 + r)*HID + t] = acc1[r];
    O2[(r0 + r)*HID + t] = acc2[r];
  }
}

// ---------------- policy head: relu(h@Wp1+bp1)@Wp2+bp2 ----------------------
__global__ void __launch_bounds__(128) k_policy(
    const float* __restrict__ h,
    const float* __restrict__ Wp1, const float* __restrict__ bp1,
    const float* __restrict__ Wp2, const float* __restrict__ bp2,
    float* __restrict__ logits) {
  __shared__ float rows[8][HID];
  __shared__ float hid[8][128];
  int t = threadIdx.x;
  int n0 = blockIdx.x * 8;
  for (int i = 0; i < 16; i++) {
    int idx = t + i * 128;
    rows[idx >> 8][idx & 255] = h[n0 * HID + idx];
  }
  __syncthreads();
  float acc[8];
  float bb = bp1[t];
  #pragma unroll
  for (int r = 0; r < 8; r++) acc[r] = bb;
  for (int k = 0; k < HID; k++) {
    float w = Wp1[k*128 + t];
    #pragma unroll
    for (int r = 0; r < 8; r++) acc[r] = fmaf(rows[r][k], w, acc[r]);
  }
  #pragma unroll
  for (int r = 0; r < 8; r++) hid[r][t] = fmaxf(acc[r], 0.f);
  __syncthreads();
  if (t < 32) {
    int r = t >> 2, i = t & 3;
    float s = bp2[i];
    for (int k = 0; k < 128; k++) s = fmaf(hid[r][k], Wp2[k*4 + i], s);
    logits[(n0 + r)*4 + i] = s;
  }
}

// ---------------- global softmax over all 40000 logits ----------------------
__global__ void __launch_bounds__(1024) k_softmax(const float* __restrict__ logits,
                                                  float* __restrict__ out) {
  const int NT = N_NODES * 4;
  __shared__ float red[16];
  int t = threadIdx.x;
  int wid = t >> 6;

  float m = -1e30f;
  for (int i = t; i < NT; i += 1024) m = fmaxf(m, logits[i]);
  #pragma unroll
  for (int msk = 1; msk < 64; msk <<= 1) m = fmaxf(m, __shfl_xor(m, msk));
  if ((t & 63) == 0) red[wid] = m;
  __syncthreads();
  m = red[0];
  #pragma unroll
  for (int i = 1; i < 16; i++) m = fmaxf(m, red[i]);
  __syncthreads();

  float s = 0.f;
  for (int i = t; i < NT; i += 1024) s += expf(logits[i] - m);
  #pragma unroll
  for (int msk = 1; msk < 64; msk <<= 1) s += __shfl_xor(s, msk);
  if ((t & 63) == 0) red[wid] = s;
  __syncthreads();
  float tot = 0.f;
  #pragma unroll
  for (int i = 0; i < 16; i++) tot += red[i];
  float inv = 1.f / tot;
  for (int i = t; i < NT; i += 1024) out[i] = expf(logits[i] - m) * inv;
}

extern "C" void kernel_launch(void* const* d_in, const int* in_sizes, int n_in,
                              void* d_out, int out_size, void* d_ws, size_t ws_size,
                              hipStream_t stream) {
  const float* x    = (const float*)d_in[0];
  const int*   ei   = (const int*)  d_in[1];
  const float* ea   = (const float*)d_in[2];
  const float* Wl1  = (const float*)d_in[3];
  const float* bl1  = (const float*)d_in[4];
  const float* Wr1  = (const float*)d_in[5];
  const float* br1  = (const float*)d_in[6];
  const float* We1  = (const float*)d_in[7];
  const float* att1 = (const float*)d_in[8];
  const float* bias1= (const float*)d_in[9];
  const float* g1   = (const float*)d_in[10];
  const float* be1  = (const float*)d_in[11];
  const float* Wl2  = (const float*)d_in[12];
  const float* bl2  = (const float*)d_in[13];
  const float* Wr2  = (const float*)d_in[14];
  const float* br2  = (const float*)d_in[15];
  const float* We2  = (const float*)d_in[16];
  const float* att2 = (const float*)d_in[17];
  const float* bias2= (const float*)d_in[18];
  const float* g2   = (const float*)d_in[19];
  const float* be2  = (const float*)d_in[20];
  const float* Wp1  = (const float*)d_in[21];
  const float* bp1  = (const float*)d_in[22];
  const float* Wp2  = (const float*)d_in[23];
  const float* bp2  = (const float*)d_in[24];
  float* out = (float*)d_out;

  const int* srcp = ei;            // edge_index row 0
  const int* dstp = ei + N_EDGES;  // edge_index row 1

  // workspace layout (ints first, then floats); big fp buffers aliased across phases
  int*   deg    = (int*)d_ws;           // 10240
  int*   cursor = deg + 10240;          // 10240
  int*   offs   = cursor + 10240;       // 10240 (needs N+1)
  int*   csrc   = offs + 10240;         // 330752
  float* asum   = (float*)(csrc + 330752);  // 10240
  float* lattr  = asum + 10240;             // 10240
  float* cea    = lattr + 10240;            // 330752
  float* xl1    = cea + 330752;             // 2560000
  float* xr1    = xl1 + 2560000;            // 2560000
  float* h1     = xr1 + 2560000;            // 2560000
  float* lg     = h1 + 2560000;             // 40960
  // aliases: xl1/xr1 dead after conv1 -> reuse for conv2 transforms; h1 dead
  // after the dual GEMM -> reuse for h2.
  float* xl2 = xl1;
  float* xr2 = xr1;
  float* h2  = h1;

  hipMemsetAsync(deg, 0, 2 * 10240 * sizeof(int), stream);   // deg + cursor
  hipMemsetAsync(asum, 0, 10240 * sizeof(float), stream);

  k_deg    <<<(N_EDGES + 255)/256, 256, 0, stream>>>(dstp, ea, deg, asum);
  k_scan   <<<1, 256, 0, stream>>>(deg, asum, offs, lattr);
  k_scatter<<<(N_AUG + 255)/256, 256, 0, stream>>>(srcp, dstp, ea, lattr, offs,
                                                   cursor, csrc, cea);
  k_xform1 <<<N_NODES, 64, 0, stream>>>(x, Wl1, bl1, Wr1, br1, xl1, xr1);
  k_conv<16><<<N_NODES, 64, 0, stream>>>(xl1, xr1, offs, csrc, cea,
                                         We1, att1, bias1, g1, be1, h1);
  k_gemm_dual<<<N_NODES/16, 256, 0, stream>>>(h1, Wl2, bl2, Wr2, br2, xl2, xr2);
  k_conv<64><<<N_NODES, 64, 0, stream>>>(xl2, xr2, offs, csrc, cea,
                                         We2, att2, bias2, g2, be2, h2);
  k_policy <<<N_NODES/8, 128, 0, stream>>>(h2, Wp1, bp1, Wp2, bp2, lg);
  k_softmax<<<1, 1024, 0, stream>>>(lg, out);
}

// Round 2
// 423.712 us; speedup vs baseline: 1.0198x; 1.0198x over previous
//
#include <hip/hip_runtime.h>
#include <math.h>

#define N_NODES 10000
#define N_EDGES 320000
#define N_AUG   (N_EDGES + N_NODES)
#define HID     256

// ---------------- degree + edge_attr segment sum ----------------
__global__ void k_deg(const int* __restrict__ dst, const float* __restrict__ ea,
                      int* __restrict__ deg, float* __restrict__ asum) {
  int e = blockIdx.x * blockDim.x + threadIdx.x;
  if (e < N_EDGES) {
    int d = dst[e];
    atomicAdd(&deg[d], 1);
    atomicAdd(&asum[d], ea[e]);
  }
}

// ---------------- exclusive scan of (deg+1) over 10000 nodes, + loop_attr ----
__global__ void k_scan(const int* __restrict__ deg, const float* __restrict__ asum,
                       int* __restrict__ offs, float* __restrict__ lattr) {
  __shared__ int part[256];
  __shared__ int excl[257];
  int t = threadIdx.x;
  int base = t * 40;
  int s = 0;
  for (int i = 0; i < 40; i++) {
    int n = base + i;
    if (n < N_NODES) s += deg[n] + 1;
  }
  part[t] = s;
  __syncthreads();
  if (t == 0) {
    int run = 0;
    for (int i = 0; i < 256; i++) { excl[i] = run; run += part[i]; }
    excl[256] = run;
  }
  __syncthreads();
  int run = excl[t];
  for (int i = 0; i < 40; i++) {
    int n = base + i;
    if (n < N_NODES) {
      offs[n] = run;
      int d = deg[n];
      run += d + 1;
      lattr[n] = asum[n] / (float)max(d, 1);
    }
  }
  if (t == 0) offs[N_NODES] = excl[256];
}

// ---------------- scatter edges (incl. self loops) into CSR by dst ----------
__global__ void k_scatter(const int* __restrict__ src, const int* __restrict__ dst,
                          const float* __restrict__ ea, const float* __restrict__ lattr,
                          const int* __restrict__ offs, int* __restrict__ cursor,
                          int* __restrict__ csrc, float* __restrict__ cea) {
  int e = blockIdx.x * blockDim.x + threadIdx.x;
  if (e >= N_AUG) return;
  int s, d; float a;
  if (e < N_EDGES) { s = src[e]; d = dst[e]; a = ea[e]; }
  else             { s = e - N_EDGES; d = s; a = lattr[s]; }
  int pos = offs[d] + atomicAdd(&cursor[d], 1);
  csrc[pos] = s;
  cea[pos]  = a;
}

// ---------------- conv1 node transform: x(N,4) @ W(4,256) + b  (xl and xr) --
__global__ void __launch_bounds__(64) k_xform1(
    const float* __restrict__ x,
    const float* __restrict__ Wl, const float* __restrict__ bl,
    const float* __restrict__ Wr, const float* __restrict__ br,
    float* __restrict__ xl, float* __restrict__ xr) {
  int n = blockIdx.x;
  int c = 4 * threadIdx.x;
  float x0 = x[n*4+0], x1 = x[n*4+1], x2 = x[n*4+2], x3 = x[n*4+3];

  float4 w0 = *(const float4*)&Wl[0*HID + c];
  float4 w1 = *(const float4*)&Wl[1*HID + c];
  float4 w2 = *(const float4*)&Wl[2*HID + c];
  float4 w3 = *(const float4*)&Wl[3*HID + c];
  float4 b  = *(const float4*)&bl[c];
  float4 o;
  o.x = fmaf(x0,w0.x, fmaf(x1,w1.x, fmaf(x2,w2.x, fmaf(x3,w3.x, b.x))));
  o.y = fmaf(x0,w0.y, fmaf(x1,w1.y, fmaf(x2,w2.y, fmaf(x3,w3.y, b.y))));
  o.z = fmaf(x0,w0.z, fmaf(x1,w1.z, fmaf(x2,w2.z, fmaf(x3,w3.z, b.z))));
  o.w = fmaf(x0,w0.w, fmaf(x1,w1.w, fmaf(x2,w2.w, fmaf(x3,w3.w, b.w))));
  *(float4*)&xl[n*HID + c] = o;

  w0 = *(const float4*)&Wr[0*HID + c];
  w1 = *(const float4*)&Wr[1*HID + c];
  w2 = *(const float4*)&Wr[2*HID + c];
  w3 = *(const float4*)&Wr[3*HID + c];
  b  = *(const float4*)&br[c];
  o.x = fmaf(x0,w0.x, fmaf(x1,w1.x, fmaf(x2,w2.x, fmaf(x3,w3.x, b.x))));
  o.y = fmaf(x0,w0.y, fmaf(x1,w1.y, fmaf(x2,w2.y, fmaf(x3,w3.y, b.y))));
  o.z = fmaf(x0,w0.z, fmaf(x1,w1.z, fmaf(x2,w2.z, fmaf(x3,w3.z, b.z))));
  o.w = fmaf(x0,w0.w, fmaf(x1,w1.w, fmaf(x2,w2.w, fmaf(x3,w3.w, b.w))));
  *(float4*)&xr[n*HID + c] = o;
}

// ---------------- fused GATv2 aggregation + bias + LayerNorm + ReLU ---------
// One wave (64 lanes) per dst node; lane l owns channels 4l..4l+3.
// WRED = reduction width: 16 -> 4 heads of 64 ch, 64 -> 1 head of 256 ch.
// 2-edge unroll: two independent 1KB row gathers in flight per iteration.
template<int WRED>
__global__ void __launch_bounds__(64) k_conv(
    const float* __restrict__ xl, const float* __restrict__ xr,
    const int* __restrict__ offs, const int* __restrict__ csrc,
    const float* __restrict__ cea,
    const float* __restrict__ We, const float* __restrict__ att,
    const float* __restrict__ bias, const float* __restrict__ g,
    const float* __restrict__ be, float* __restrict__ hout) {
  int n = blockIdx.x;
  int c = 4 * threadIdx.x;
  float4 r4 = *(const float4*)&xr[n*HID + c];
  float4 we = *(const float4*)&We[c];
  float4 at = *(const float4*)&att[c];
  int js = offs[n], je = offs[n+1];

  float M = -1e30f, D = 0.f;
  float a0 = 0.f, a1 = 0.f, a2 = 0.f, a3 = 0.f;

  int j = js;
  for (; j + 1 < je; j += 2) {
    int s0 = csrc[j], s1 = csrc[j+1];
    float av0 = cea[j], av1 = cea[j+1];
    float4 xs0 = *(const float4*)&xl[s0*HID + c];
    float4 xs1 = *(const float4*)&xl[s1*HID + c];

    float m0 = xs0.x + r4.x + av0*we.x; m0 = m0 > 0.f ? m0 : 0.2f*m0;
    float m1 = xs0.y + r4.y + av0*we.y; m1 = m1 > 0.f ? m1 : 0.2f*m1;
    float m2 = xs0.z + r4.z + av0*we.z; m2 = m2 > 0.f ? m2 : 0.2f*m2;
    float m3 = xs0.w + r4.w + av0*we.w; m3 = m3 > 0.f ? m3 : 0.2f*m3;
    float p0 = m0*at.x + m1*at.y + m2*at.z + m3*at.w;

    m0 = xs1.x + r4.x + av1*we.x; m0 = m0 > 0.f ? m0 : 0.2f*m0;
    m1 = xs1.y + r4.y + av1*we.y; m1 = m1 > 0.f ? m1 : 0.2f*m1;
    m2 = xs1.z + r4.z + av1*we.z; m2 = m2 > 0.f ? m2 : 0.2f*m2;
    m3 = xs1.w + r4.w + av1*we.w; m3 = m3 > 0.f ? m3 : 0.2f*m3;
    float p1 = m0*at.x + m1*at.y + m2*at.z + m3*at.w;

    #pragma unroll
    for (int msk = 1; msk < WRED; msk <<= 1) {
      p0 += __shfl_xor(p0, msk);
      p1 += __shfl_xor(p1, msk);
    }
    float newM = fmaxf(M, fmaxf(p0, p1));
    float sc = expf(M - newM);
    float e0 = expf(p0 - newM);
    float e1 = expf(p1 - newM);
    D  = fmaf(D, sc, e0 + e1);
    a0 = fmaf(e1, xs1.x, fmaf(e0, xs0.x, a0 * sc));
    a1 = fmaf(e1, xs1.y, fmaf(e0, xs0.y, a1 * sc));
    a2 = fmaf(e1, xs1.z, fmaf(e0, xs0.z, a2 * sc));
    a3 = fmaf(e1, xs1.w, fmaf(e0, xs0.w, a3 * sc));
    M = newM;
  }
  if (j < je) {
    int s0 = csrc[j];
    float av0 = cea[j];
    float4 xs0 = *(const float4*)&xl[s0*HID + c];
    float m0 = xs0.x + r4.x + av0*we.x; m0 = m0 > 0.f ? m0 : 0.2f*m0;
    float m1 = xs0.y + r4.y + av0*we.y; m1 = m1 > 0.f ? m1 : 0.2f*m1;
    float m2 = xs0.z + r4.z + av0*we.z; m2 = m2 > 0.f ? m2 : 0.2f*m2;
    float m3 = xs0.w + r4.w + av0*we.w; m3 = m3 > 0.f ? m3 : 0.2f*m3;
    float p0 = m0*at.x + m1*at.y + m2*at.z + m3*at.w;
    #pragma unroll
    for (int msk = 1; msk < WRED; msk <<= 1) p0 += __shfl_xor(p0, msk);
    float newM = fmaxf(M, p0);
    float sc = expf(M - newM);
    float e0 = expf(p0 - newM);
    D  = fmaf(D, sc, e0);
    a0 = fmaf(e0, xs0.x, a0 * sc);
    a1 = fmaf(e0, xs0.y, a1 * sc);
    a2 = fmaf(e0, xs0.z, a2 * sc);
    a3 = fmaf(e0, xs0.w, a3 * sc);
  }

  float inv = 1.f / D;
  float4 b4 = *(const float4*)&bias[c];
  float o0 = fmaf(a0, inv, b4.x);
  float o1 = fmaf(a1, inv, b4.y);
  float o2 = fmaf(a2, inv, b4.z);
  float o3 = fmaf(a3, inv, b4.w);

  // LayerNorm over 256 channels (whole wave) + affine + ReLU
  float s = o0 + o1 + o2 + o3;
  #pragma unroll
  for (int msk = 1; msk < 64; msk <<= 1) s += __shfl_xor(s, msk);
  float mu = s * (1.f / 256.f);
  float d0 = o0 - mu, d1 = o1 - mu, d2 = o2 - mu, d3 = o3 - mu;
  float sq = d0*d0 + d1*d1 + d2*d2 + d3*d3;
  #pragma unroll
  for (int msk = 1; msk < 64; msk <<= 1) sq += __shfl_xor(sq, msk);
  float rstd = rsqrtf(sq * (1.f / 256.f) + 1e-5f);
  float4 g4  = *(const float4*)&g[c];
  float4 be4 = *(const float4*)&be[c];
  float4 o;
  o.x = fmaxf(fmaf(d0 * rstd, g4.x, be4.x), 0.f);
  o.y = fmaxf(fmaf(d1 * rstd, g4.y, be4.y), 0.f);
  o.z = fmaxf(fmaf(d2 * rstd, g4.z, be4.z), 0.f);
  o.w = fmaxf(fmaf(d3 * rstd, g4.w, be4.w), 0.f);
  *(float4*)&hout[n*HID + c] = o;
}

// ---------------- dual GEMM: O1 = A@W1+b1, O2 = A@W2+b2  (A: 10000x256) -----
// A-operand addresses are wave-uniform -> scalar loads (SMEM pipe), no LDS.
__global__ void __launch_bounds__(256) k_gemm_dual(
    const float* __restrict__ A,
    const float* __restrict__ W1, const float* __restrict__ b1,
    const float* __restrict__ W2, const float* __restrict__ b2,
    float* __restrict__ O1, float* __restrict__ O2) {
  int t = threadIdx.x;
  int r0 = blockIdx.x * 16;
  const float* __restrict__ Ab = A + r0 * HID;
  float acc1[16], acc2[16];
  float bb1 = b1[t], bb2 = b2[t];
  #pragma unroll
  for (int r = 0; r < 16; r++) { acc1[r] = bb1; acc2[r] = bb2; }
  #pragma unroll 4
  for (int k = 0; k < HID; k++) {
    float w1 = W1[k*HID + t];
    float w2 = W2[k*HID + t];
    #pragma unroll
    for (int r = 0; r < 16; r++) {
      float av = Ab[r*HID + k];          // uniform -> s_load
      acc1[r] = fmaf(av, w1, acc1[r]);
      acc2[r] = fmaf(av, w2, acc2[r]);
    }
  }
  for (int r = 0; r < 16; r++) {
    O1[(r0 + r)*HID + t] = acc1[r];
    O2[(r0 + r)*HID + t] = acc2[r];
  }
}

// ---------------- policy head: relu(h@Wp1+bp1)@Wp2+bp2 ----------------------
// Phase 1: scalar-A GEMM (16 rows x 128 cols per block), no LDS broadcast.
// Phase 2: hid staged in LDS (stride 132 to spread banks), 64 lanes finish.
__global__ void __launch_bounds__(128) k_policy(
    const float* __restrict__ h,
    const float* __restrict__ Wp1, const float* __restrict__ bp1,
    const float* __restrict__ Wp2, const float* __restrict__ bp2,
    float* __restrict__ logits) {
  __shared__ float hid[16][132];
  int t = threadIdx.x;
  int n0 = blockIdx.x * 16;
  const float* __restrict__ hb = h + n0 * HID;
  float acc[16];
  float bb = bp1[t];
  #pragma unroll
  for (int r = 0; r < 16; r++) acc[r] = bb;
  #pragma unroll 4
  for (int k = 0; k < HID; k++) {
    float w = Wp1[k*128 + t];
    #pragma unroll
    for (int r = 0; r < 16; r++) acc[r] = fmaf(hb[r*HID + k], w, acc[r]);
  }
  #pragma unroll
  for (int r = 0; r < 16; r++) hid[r][t] = fmaxf(acc[r], 0.f);
  __syncthreads();
  if (t < 64) {
    int r = t >> 2, i = t & 3;
    float s = bp2[i];
    for (int k = 0; k < 128; k++) s = fmaf(hid[r][k], Wp2[k*4 + i], s);
    logits[(n0 + r)*4 + i] = s;
  }
}

// ---------------- global softmax over all 40000 logits ----------------------
__global__ void __launch_bounds__(1024) k_softmax(const float* __restrict__ logits,
                                                  float* __restrict__ out) {
  const int NT = N_NODES * 4;
  __shared__ float red[16];
  int t = threadIdx.x;
  int wid = t >> 6;

  float m = -1e30f;
  for (int i = t; i < NT; i += 1024) m = fmaxf(m, logits[i]);
  #pragma unroll
  for (int msk = 1; msk < 64; msk <<= 1) m = fmaxf(m, __shfl_xor(m, msk));
  if ((t & 63) == 0) red[wid] = m;
  __syncthreads();
  m = red[0];
  #pragma unroll
  for (int i = 1; i < 16; i++) m = fmaxf(m, red[i]);
  __syncthreads();

  float s = 0.f;
  for (int i = t; i < NT; i += 1024) s += expf(logits[i] - m);
  #pragma unroll
  for (int msk = 1; msk < 64; msk <<= 1) s += __shfl_xor(s, msk);
  if ((t & 63) == 0) red[wid] = s;
  __syncthreads();
  float tot = 0.f;
  #pragma unroll
  for (int i = 0; i < 16; i++) tot += red[i];
  float inv = 1.f / tot;
  for (int i = t; i < NT; i += 1024) out[i] = expf(logits[i] - m) * inv;
}

extern "C" void kernel_launch(void* const* d_in, const int* in_sizes, int n_in,
                              void* d_out, int out_size, void* d_ws, size_t ws_size,
                              hipStream_t stream) {
  const float* x    = (const float*)d_in[0];
  const int*   ei   = (const int*)  d_in[1];
  const float* ea   = (const float*)d_in[2];
  const float* Wl1  = (const float*)d_in[3];
  const float* bl1  = (const float*)d_in[4];
  const float* Wr1  = (const float*)d_in[5];
  const float* br1  = (const float*)d_in[6];
  const float* We1  = (const float*)d_in[7];
  const float* att1 = (const float*)d_in[8];
  const float* bias1= (const float*)d_in[9];
  const float* g1   = (const float*)d_in[10];
  const float* be1  = (const float*)d_in[11];
  const float* Wl2  = (const float*)d_in[12];
  const float* bl2  = (const float*)d_in[13];
  const float* Wr2  = (const float*)d_in[14];
  const float* br2  = (const float*)d_in[15];
  const float* We2  = (const float*)d_in[16];
  const float* att2 = (const float*)d_in[17];
  const float* bias2= (const float*)d_in[18];
  const float* g2   = (const float*)d_in[19];
  const float* be2  = (const float*)d_in[20];
  const float* Wp1  = (const float*)d_in[21];
  const float* bp1  = (const float*)d_in[22];
  const float* Wp2  = (const float*)d_in[23];
  const float* bp2  = (const float*)d_in[24];
  float* out = (float*)d_out;

  const int* srcp = ei;            // edge_index row 0
  const int* dstp = ei + N_EDGES;  // edge_index row 1

  // workspace layout (ints first, then floats); big fp buffers aliased across phases
  int*   deg    = (int*)d_ws;           // 10240
  int*   cursor = deg + 10240;          // 10240
  int*   offs   = cursor + 10240;       // 10240 (needs N+1)
  int*   csrc   = offs + 10240;         // 330752
  float* asum   = (float*)(csrc + 330752);  // 10240
  float* lattr  = asum + 10240;             // 10240
  float* cea    = lattr + 10240;            // 330752
  float* xl1    = cea + 330752;             // 2560000
  float* xr1    = xl1 + 2560000;            // 2560000
  float* h1     = xr1 + 2560000;            // 2560000
  float* lg     = h1 + 2560000;             // 40960
  float* xl2 = xl1;
  float* xr2 = xr1;
  float* h2  = h1;

  hipMemsetAsync(deg, 0, 2 * 10240 * sizeof(int), stream);   // deg + cursor
  hipMemsetAsync(asum, 0, 10240 * sizeof(float), stream);

  k_deg    <<<(N_EDGES + 255)/256, 256, 0, stream>>>(dstp, ea, deg, asum);
  k_scan   <<<1, 256, 0, stream>>>(deg, asum, offs, lattr);
  k_scatter<<<(N_AUG + 255)/256, 256, 0, stream>>>(srcp, dstp, ea, lattr, offs,
                                                   cursor, csrc, cea);
  k_xform1 <<<N_NODES, 64, 0, stream>>>(x, Wl1, bl1, Wr1, br1, xl1, xr1);
  k_conv<16><<<N_NODES, 64, 0, stream>>>(xl1, xr1, offs, csrc, cea,
                                         We1, att1, bias1, g1, be1, h1);
  k_gemm_dual<<<N_NODES/16, 256, 0, stream>>>(h1, Wl2, bl2, Wr2, br2, xl2, xr2);
  k_conv<64><<<N_NODES, 64, 0, stream>>>(xl2, xr2, offs, csrc, cea,
                                         We2, att2, bias2, g2, be2, h2);
  k_policy <<<N_NODES/8/2, 128, 0, stream>>>(h2, Wp1, bp1, Wp2, bp2, lg);
  k_softmax<<<1, 1024, 0, stream>>>(lg, out);
}

// Round 3
// 396.602 us; speedup vs baseline: 1.0895x; 1.0684x over previous
//
#include <hip/hip_runtime.h>
#include <math.h>

#define N_NODES 10000
#define N_EDGES 320000
#define N_AUG   (N_EDGES + N_NODES)
#define HID     256

// ---------------- degree + edge_attr segment sum ----------------
__global__ void k_deg(const int* __restrict__ dst, const float* __restrict__ ea,
                      int* __restrict__ deg, float* __restrict__ asum) {
  int e = blockIdx.x * blockDim.x + threadIdx.x;
  if (e < N_EDGES) {
    int d = dst[e];
    atomicAdd(&deg[d], 1);
    atomicAdd(&asum[d], ea[e]);
  }
}

// ------- exclusive scan of (deg+1) over 10000 nodes (parallel), + loop_attr --
__global__ void __launch_bounds__(256) k_scan(
    const int* __restrict__ deg, const float* __restrict__ asum,
    int* __restrict__ offs, float* __restrict__ lattr) {
  __shared__ int wsum[4];
  int t = threadIdx.x;
  int base = t * 40;
  int s = 0;
  for (int i = 0; i < 40; i++) {
    int n = base + i;
    if (n < N_NODES) s += deg[n] + 1;
  }
  // wave-level inclusive scan of s
  int v = s;
  #pragma unroll
  for (int d = 1; d < 64; d <<= 1) {
    int u = __shfl_up(v, d);
    if ((t & 63) >= d) v += u;
  }
  if ((t & 63) == 63) wsum[t >> 6] = v;
  __syncthreads();
  int wb = 0;
  for (int i = 0; i < (t >> 6); i++) wb += wsum[i];
  int run = wb + v - s;   // exclusive prefix for this thread's chunk
  for (int i = 0; i < 40; i++) {
    int n = base + i;
    if (n < N_NODES) {
      offs[n] = run;
      int d = deg[n];
      run += d + 1;
      lattr[n] = asum[n] / (float)max(d, 1);
    }
  }
  if (t == 255) offs[N_NODES] = wb + v;
}

// ------- scatter edges (incl. self loops) into CSR by dst, packed (src,ea) --
__global__ void k_scatter(const int* __restrict__ src, const int* __restrict__ dst,
                          const float* __restrict__ ea, const float* __restrict__ lattr,
                          const int* __restrict__ offs, int* __restrict__ cursor,
                          int2* __restrict__ cpk) {
  int e = blockIdx.x * blockDim.x + threadIdx.x;
  if (e >= N_AUG) return;
  int s, d; float a;
  if (e < N_EDGES) { s = src[e]; d = dst[e]; a = ea[e]; }
  else             { s = e - N_EDGES; d = s; a = lattr[s]; }
  int pos = offs[d] + atomicAdd(&cursor[d], 1);
  cpk[pos] = make_int2(s, __float_as_int(a));
}

// ---------------- conv1 node transform: x(N,4) @ W(4,256) + b  (xl and xr) --
__global__ void __launch_bounds__(256) k_xform1(
    const float* __restrict__ x,
    const float* __restrict__ Wl, const float* __restrict__ bl,
    const float* __restrict__ Wr, const float* __restrict__ br,
    float* __restrict__ xl, float* __restrict__ xr) {
  int t = threadIdx.x;
  int n = blockIdx.x * 4 + (t >> 6);
  int c = 4 * (t & 63);
  float x0 = x[n*4+0], x1 = x[n*4+1], x2 = x[n*4+2], x3 = x[n*4+3];

  float4 w0 = *(const float4*)&Wl[0*HID + c];
  float4 w1 = *(const float4*)&Wl[1*HID + c];
  float4 w2 = *(const float4*)&Wl[2*HID + c];
  float4 w3 = *(const float4*)&Wl[3*HID + c];
  float4 b  = *(const float4*)&bl[c];
  float4 o;
  o.x = fmaf(x0,w0.x, fmaf(x1,w1.x, fmaf(x2,w2.x, fmaf(x3,w3.x, b.x))));
  o.y = fmaf(x0,w0.y, fmaf(x1,w1.y, fmaf(x2,w2.y, fmaf(x3,w3.y, b.y))));
  o.z = fmaf(x0,w0.z, fmaf(x1,w1.z, fmaf(x2,w2.z, fmaf(x3,w3.z, b.z))));
  o.w = fmaf(x0,w0.w, fmaf(x1,w1.w, fmaf(x2,w2.w, fmaf(x3,w3.w, b.w))));
  *(float4*)&xl[n*HID + c] = o;

  w0 = *(const float4*)&Wr[0*HID + c];
  w1 = *(const float4*)&Wr[1*HID + c];
  w2 = *(const float4*)&Wr[2*HID + c];
  w3 = *(const float4*)&Wr[3*HID + c];
  b  = *(const float4*)&br[c];
  o.x = fmaf(x0,w0.x, fmaf(x1,w1.x, fmaf(x2,w2.x, fmaf(x3,w3.x, b.x))));
  o.y = fmaf(x0,w0.y, fmaf(x1,w1.y, fmaf(x2,w2.y, fmaf(x3,w3.y, b.y))));
  o.z = fmaf(x0,w0.z, fmaf(x1,w1.z, fmaf(x2,w2.z, fmaf(x3,w3.z, b.z))));
  o.w = fmaf(x0,w0.w, fmaf(x1,w1.w, fmaf(x2,w2.w, fmaf(x3,w3.w, b.w))));
  *(float4*)&xr[n*HID + c] = o;
}

// ---------------- fused GATv2 aggregation + bias + LayerNorm + ReLU ---------
// One wave per dst node (4 nodes per 256-thread block); lane l owns 4 channels.
// WRED = reduction width: 16 -> 4 heads of 64 ch, 64 -> 1 head of 256 ch.
template<int WRED>
__global__ void __launch_bounds__(256) k_conv(
    const float* __restrict__ xl, const float* __restrict__ xr,
    const int* __restrict__ offs, const int2* __restrict__ cpk,
    const float* __restrict__ We, const float* __restrict__ att,
    const float* __restrict__ bias, const float* __restrict__ g,
    const float* __restrict__ be, float* __restrict__ hout) {
  int t = threadIdx.x;
  int n = blockIdx.x * 4 + (t >> 6);
  int c = 4 * (t & 63);
  float4 r4 = *(const float4*)&xr[n*HID + c];
  float4 we = *(const float4*)&We[c];
  float4 at = *(const float4*)&att[c];
  int js = __builtin_amdgcn_readfirstlane(offs[n]);
  int je = __builtin_amdgcn_readfirstlane(offs[n+1]);

  float M = -1e30f, D = 0.f;
  float a0 = 0.f, a1 = 0.f, a2 = 0.f, a3 = 0.f;

  int j = js;
  for (; j + 1 < je; j += 2) {
    int2 e0 = cpk[j], e1 = cpk[j+1];
    int s0 = e0.x, s1 = e1.x;
    float av0 = __int_as_float(e0.y), av1 = __int_as_float(e1.y);
    float4 xs0 = *(const float4*)&xl[s0*HID + c];
    float4 xs1 = *(const float4*)&xl[s1*HID + c];

    float m0 = xs0.x + r4.x + av0*we.x; m0 = m0 > 0.f ? m0 : 0.2f*m0;
    float m1 = xs0.y + r4.y + av0*we.y; m1 = m1 > 0.f ? m1 : 0.2f*m1;
    float m2 = xs0.z + r4.z + av0*we.z; m2 = m2 > 0.f ? m2 : 0.2f*m2;
    float m3 = xs0.w + r4.w + av0*we.w; m3 = m3 > 0.f ? m3 : 0.2f*m3;
    float p0 = m0*at.x + m1*at.y + m2*at.z + m3*at.w;

    m0 = xs1.x + r4.x + av1*we.x; m0 = m0 > 0.f ? m0 : 0.2f*m0;
    m1 = xs1.y + r4.y + av1*we.y; m1 = m1 > 0.f ? m1 : 0.2f*m1;
    m2 = xs1.z + r4.z + av1*we.z; m2 = m2 > 0.f ? m2 : 0.2f*m2;
    m3 = xs1.w + r4.w + av1*we.w; m3 = m3 > 0.f ? m3 : 0.2f*m3;
    float p1 = m0*at.x + m1*at.y + m2*at.z + m3*at.w;

    #pragma unroll
    for (int msk = 1; msk < WRED; msk <<= 1) {
      p0 += __shfl_xor(p0, msk);
      p1 += __shfl_xor(p1, msk);
    }
    float newM = fmaxf(M, fmaxf(p0, p1));
    float sc = expf(M - newM);
    float e0x = expf(p0 - newM);
    float e1x = expf(p1 - newM);
    D  = fmaf(D, sc, e0x + e1x);
    a0 = fmaf(e1x, xs1.x, fmaf(e0x, xs0.x, a0 * sc));
    a1 = fmaf(e1x, xs1.y, fmaf(e0x, xs0.y, a1 * sc));
    a2 = fmaf(e1x, xs1.z, fmaf(e0x, xs0.z, a2 * sc));
    a3 = fmaf(e1x, xs1.w, fmaf(e0x, xs0.w, a3 * sc));
    M = newM;
  }
  if (j < je) {
    int2 e0 = cpk[j];
    int s0 = e0.x;
    float av0 = __int_as_float(e0.y);
    float4 xs0 = *(const float4*)&xl[s0*HID + c];
    float m0 = xs0.x + r4.x + av0*we.x; m0 = m0 > 0.f ? m0 : 0.2f*m0;
    float m1 = xs0.y + r4.y + av0*we.y; m1 = m1 > 0.f ? m1 : 0.2f*m1;
    float m2 = xs0.z + r4.z + av0*we.z; m2 = m2 > 0.f ? m2 : 0.2f*m2;
    float m3 = xs0.w + r4.w + av0*we.w; m3 = m3 > 0.f ? m3 : 0.2f*m3;
    float p0 = m0*at.x + m1*at.y + m2*at.z + m3*at.w;
    #pragma unroll
    for (int msk = 1; msk < WRED; msk <<= 1) p0 += __shfl_xor(p0, msk);
    float newM = fmaxf(M, p0);
    float sc = expf(M - newM);
    float e0x = expf(p0 - newM);
    D  = fmaf(D, sc, e0x);
    a0 = fmaf(e0x, xs0.x, a0 * sc);
    a1 = fmaf(e0x, xs0.y, a1 * sc);
    a2 = fmaf(e0x, xs0.z, a2 * sc);
    a3 = fmaf(e0x, xs0.w, a3 * sc);
  }

  float inv = 1.f / D;
  float4 b4 = *(const float4*)&bias[c];
  float o0 = fmaf(a0, inv, b4.x);
  float o1 = fmaf(a1, inv, b4.y);
  float o2 = fmaf(a2, inv, b4.z);
  float o3 = fmaf(a3, inv, b4.w);

  // LayerNorm over 256 channels (whole wave) + affine + ReLU
  float s = o0 + o1 + o2 + o3;
  #pragma unroll
  for (int msk = 1; msk < 64; msk <<= 1) s += __shfl_xor(s, msk);
  float mu = s * (1.f / 256.f);
  float d0 = o0 - mu, d1 = o1 - mu, d2 = o2 - mu, d3 = o3 - mu;
  float sq = d0*d0 + d1*d1 + d2*d2 + d3*d3;
  #pragma unroll
  for (int msk = 1; msk < 64; msk <<= 1) sq += __shfl_xor(sq, msk);
  float rstd = rsqrtf(sq * (1.f / 256.f) + 1e-5f);
  float4 g4  = *(const float4*)&g[c];
  float4 be4 = *(const float4*)&be[c];
  float4 o;
  o.x = fmaxf(fmaf(d0 * rstd, g4.x, be4.x), 0.f);
  o.y = fmaxf(fmaf(d1 * rstd, g4.y, be4.y), 0.f);
  o.z = fmaxf(fmaf(d2 * rstd, g4.z, be4.z), 0.f);
  o.w = fmaxf(fmaf(d3 * rstd, g4.w, be4.w), 0.f);
  *(float4*)&hout[n*HID + c] = o;
}

// ---------------- dual GEMM: O1 = A@W1+b1, O2 = A@W2+b2  (A: 10000x256) -----
// Register-tiled 64x64 (x2 outputs), 4x4 per thread, LDS-staged, ds_read_b128.
__global__ void __launch_bounds__(256) k_gemm_dual(
    const float* __restrict__ A,
    const float* __restrict__ W1, const float* __restrict__ b1,
    const float* __restrict__ W2, const float* __restrict__ b2,
    float* __restrict__ O1, float* __restrict__ O2) {
  __shared__ float As[16][64];
  __shared__ float Ws1[16][64];
  __shared__ float Ws2[16][64];
  int t = threadIdx.x;
  int r0 = blockIdx.x * 64;
  int c0 = blockIdx.y * 64;
  int tx = t & 15, ty = t >> 4;

  float acc1[4][4] = {{0}};
  float acc2[4][4] = {{0}};

  int ar = t >> 2;                 // 0..63 row in tile
  int ak = (t & 3) * 4;            // 0..12 k in block
  int arow = min(r0 + ar, N_NODES - 1);
  int wk = t >> 4;                 // 0..15
  int wc = (t & 15) * 4;           // 0..60

  for (int k0 = 0; k0 < HID; k0 += 16) {
    float4 av  = *(const float4*)&A [arow*HID + k0 + ak];
    float4 w1v = *(const float4*)&W1[(k0+wk)*HID + c0 + wc];
    float4 w2v = *(const float4*)&W2[(k0+wk)*HID + c0 + wc];
    __syncthreads();
    As[ak+0][ar] = av.x; As[ak+1][ar] = av.y;
    As[ak+2][ar] = av.z; As[ak+3][ar] = av.w;
    *(float4*)&Ws1[wk][wc] = w1v;
    *(float4*)&Ws2[wk][wc] = w2v;
    __syncthreads();
    #pragma unroll
    for (int k = 0; k < 16; k++) {
      float4 a4  = *(const float4*)&As [k][4*ty];
      float4 w14 = *(const float4*)&Ws1[k][4*tx];
      float4 w24 = *(const float4*)&Ws2[k][4*tx];
      const float aa[4] = {a4.x, a4.y, a4.z, a4.w};
      const float ww1[4] = {w14.x, w14.y, w14.z, w14.w};
      const float ww2[4] = {w24.x, w24.y, w24.z, w24.w};
      #pragma unroll
      for (int i = 0; i < 4; i++)
        #pragma unroll
        for (int jj = 0; jj < 4; jj++) {
          acc1[i][jj] = fmaf(aa[i], ww1[jj], acc1[i][jj]);
          acc2[i][jj] = fmaf(aa[i], ww2[jj], acc2[i][jj]);
        }
    }
  }
  int cbase = c0 + 4*tx;
  float4 b1v = *(const float4*)&b1[cbase];
  float4 b2v = *(const float4*)&b2[cbase];
  #pragma unroll
  for (int i = 0; i < 4; i++) {
    int r = r0 + 4*ty + i;
    if (r < N_NODES) {
      float4 o1 = {acc1[i][0]+b1v.x, acc1[i][1]+b1v.y, acc1[i][2]+b1v.z, acc1[i][3]+b1v.w};
      float4 o2 = {acc2[i][0]+b2v.x, acc2[i][1]+b2v.y, acc2[i][2]+b2v.z, acc2[i][3]+b2v.w};
      *(float4*)&O1[r*HID + cbase] = o1;
      *(float4*)&O2[r*HID + cbase] = o2;
    }
  }
}

// ---------------- fused policy head: logits = relu(h@Wp1+bp1)@Wp2+bp2 -------
// Phase 1: 64x128 register-tiled GEMM (4x8/thread), relu -> LDS hid tile.
// Phase 2: per-(node,i) 128-dot from LDS.
__global__ void __launch_bounds__(256) k_policy(
    const float* __restrict__ h,
    const float* __restrict__ Wp1, const float* __restrict__ bp1,
    const float* __restrict__ Wp2, const float* __restrict__ bp2,
    float* __restrict__ logits) {
  __shared__ float As[16][64];
  __shared__ float Ws[16][128];
  __shared__ float hidl[64][132];
  int t = threadIdx.x;
  int r0 = blockIdx.x * 64;
  int tx = t & 15, ty = t >> 4;   // cols 8*tx.. , rows 4*ty..

  float acc[4][8] = {{0}};

  int ar = t >> 2;
  int ak = (t & 3) * 4;
  int arow = min(r0 + ar, N_NODES - 1);
  int wk = t >> 4;                 // 0..15
  int wc = (t & 15) * 8;           // 0..120

  for (int k0 = 0; k0 < HID; k0 += 16) {
    float4 av  = *(const float4*)&h[arow*HID + k0 + ak];
    float4 wva = *(const float4*)&Wp1[(k0+wk)*128 + wc];
    float4 wvb = *(const float4*)&Wp1[(k0+wk)*128 + wc + 4];
    __syncthreads();
    As[ak+0][ar] = av.x; As[ak+1][ar] = av.y;
    As[ak+2][ar] = av.z; As[ak+3][ar] = av.w;
    *(float4*)&Ws[wk][wc]     = wva;
    *(float4*)&Ws[wk][wc + 4] = wvb;
    __syncthreads();
    #pragma unroll
    for (int k = 0; k < 16; k++) {
      float4 a4 = *(const float4*)&As[k][4*ty];
      float4 wA = *(const float4*)&Ws[k][8*tx];
      float4 wB = *(const float4*)&Ws[k][8*tx + 4];
      const float aa[4] = {a4.x, a4.y, a4.z, a4.w};
      const float ww[8] = {wA.x, wA.y, wA.z, wA.w, wB.x, wB.y, wB.z, wB.w};
      #pragma unroll
      for (int i = 0; i < 4; i++)
        #pragma unroll
        for (int jj = 0; jj < 8; jj++)
          acc[i][jj] = fmaf(aa[i], ww[jj], acc[i][jj]);
    }
  }
  int cbase = 8*tx;
  float4 bA = *(const float4*)&bp1[cbase];
  float4 bB = *(const float4*)&bp1[cbase + 4];
  const float bb[8] = {bA.x, bA.y, bA.z, bA.w, bB.x, bB.y, bB.z, bB.w};
  #pragma unroll
  for (int i = 0; i < 4; i++) {
    int r = 4*ty + i;
    float4 oA = {fmaxf(acc[i][0]+bb[0],0.f), fmaxf(acc[i][1]+bb[1],0.f),
                 fmaxf(acc[i][2]+bb[2],0.f), fmaxf(acc[i][3]+bb[3],0.f)};
    float4 oB = {fmaxf(acc[i][4]+bb[4],0.f), fmaxf(acc[i][5]+bb[5],0.f),
                 fmaxf(acc[i][6]+bb[6],0.f), fmaxf(acc[i][7]+bb[7],0.f)};
    *(float4*)&hidl[r][cbase]     = oA;
    *(float4*)&hidl[r][cbase + 4] = oB;
  }
  __syncthreads();
  // phase 2: thread t -> node_local = t>>2, output i = t&3
  int nl = t >> 2, i = t & 3;
  float s = bp2[i];
  for (int k = 0; k < 128; k += 4) {
    float4 hv = *(const float4*)&hidl[nl][k];
    s = fmaf(hv.x, Wp2[(k+0)*4 + i],
        fmaf(hv.y, Wp2[(k+1)*4 + i],
        fmaf(hv.z, Wp2[(k+2)*4 + i],
        fmaf(hv.w, Wp2[(k+3)*4 + i], s))));
  }
  int n = r0 + nl;
  if (n < N_NODES) logits[n*4 + i] = s;
}

// ---------------- global softmax over all 40000 logits ----------------------
__global__ void __launch_bounds__(1024) k_softmax(const float* __restrict__ logits,
                                                  float* __restrict__ out) {
  const int NT = N_NODES * 4;
  __shared__ float red[16];
  int t = threadIdx.x;
  int wid = t >> 6;

  float m = -1e30f;
  for (int i = t; i < NT; i += 1024) m = fmaxf(m, logits[i]);
  #pragma unroll
  for (int msk = 1; msk < 64; msk <<= 1) m = fmaxf(m, __shfl_xor(m, msk));
  if ((t & 63) == 0) red[wid] = m;
  __syncthreads();
  m = red[0];
  #pragma unroll
  for (int i = 1; i < 16; i++) m = fmaxf(m, red[i]);
  __syncthreads();

  float s = 0.f;
  for (int i = t; i < NT; i += 1024) s += expf(logits[i] - m);
  #pragma unroll
  for (int msk = 1; msk < 64; msk <<= 1) s += __shfl_xor(s, msk);
  if ((t & 63) == 0) red[wid] = s;
  __syncthreads();
  float tot = 0.f;
  #pragma unroll
  for (int i = 0; i < 16; i++) tot += red[i];
  float inv = 1.f / tot;
  for (int i = t; i < NT; i += 1024) out[i] = expf(logits[i] - m) * inv;
}

extern "C" void kernel_launch(void* const* d_in, const int* in_sizes, int n_in,
                              void* d_out, int out_size, void* d_ws, size_t ws_size,
                              hipStream_t stream) {
  const float* x    = (const float*)d_in[0];
  const int*   ei   = (const int*)  d_in[1];
  const float* ea   = (const float*)d_in[2];
  const float* Wl1  = (const float*)d_in[3];
  const float* bl1  = (const float*)d_in[4];
  const float* Wr1  = (const float*)d_in[5];
  const float* br1  = (const float*)d_in[6];
  const float* We1  = (const float*)d_in[7];
  const float* att1 = (const float*)d_in[8];
  const float* bias1= (const float*)d_in[9];
  const float* g1   = (const float*)d_in[10];
  const float* be1  = (const float*)d_in[11];
  const float* Wl2  = (const float*)d_in[12];
  const float* bl2  = (const float*)d_in[13];
  const float* Wr2  = (const float*)d_in[14];
  const float* br2  = (const float*)d_in[15];
  const float* We2  = (const float*)d_in[16];
  const float* att2 = (const float*)d_in[17];
  const float* bias2= (const float*)d_in[18];
  const float* g2   = (const float*)d_in[19];
  const float* be2  = (const float*)d_in[20];
  const float* Wp1  = (const float*)d_in[21];
  const float* bp1  = (const float*)d_in[22];
  const float* Wp2  = (const float*)d_in[23];
  const float* bp2  = (const float*)d_in[24];
  float* out = (float*)d_out;

  const int* srcp = ei;            // edge_index row 0
  const int* dstp = ei + N_EDGES;  // edge_index row 1

  // workspace layout
  int*   deg    = (int*)d_ws;               // 10240
  int*   cursor = deg + 10240;              // 10240
  int*   offs   = cursor + 10240;           // 10240 (needs N+1)
  float* asum   = (float*)(offs + 10240);   // 10240
  float* lattr  = asum + 10240;             // 10240
  int2*  cpk    = (int2*)(lattr + 10240);   // 330752 int2 (8B aligned: 204800B off)
  float* xl1    = (float*)(cpk + 330752);   // 2560000
  float* xr1    = xl1 + 2560000;            // 2560000
  float* h1     = xr1 + 2560000;            // 2560000
  float* lg     = h1 + 2560000;             // 40960
  float* xl2 = xl1;
  float* xr2 = xr1;
  float* h2  = h1;

  hipMemsetAsync(deg, 0, 2 * 10240 * sizeof(int), stream);   // deg + cursor
  hipMemsetAsync(asum, 0, 10240 * sizeof(float), stream);

  k_deg    <<<(N_EDGES + 255)/256, 256, 0, stream>>>(dstp, ea, deg, asum);
  k_scan   <<<1, 256, 0, stream>>>(deg, asum, offs, lattr);
  k_scatter<<<(N_AUG + 255)/256, 256, 0, stream>>>(srcp, dstp, ea, lattr, offs,
                                                   cursor, cpk);
  k_xform1 <<<N_NODES/4, 256, 0, stream>>>(x, Wl1, bl1, Wr1, br1, xl1, xr1);
  k_conv<16><<<N_NODES/4, 256, 0, stream>>>(xl1, xr1, offs, cpk,
                                            We1, att1, bias1, g1, be1, h1);
  k_gemm_dual<<<dim3(157, 4), 256, 0, stream>>>(h1, Wl2, bl2, Wr2, br2, xl2, xr2);
  k_conv<64><<<N_NODES/4, 256, 0, stream>>>(xl2, xr2, offs, cpk,
                                            We2, att2, bias2, g2, be2, h2);
  k_policy <<<157, 256, 0, stream>>>(h2, Wp1, bp1, Wp2, bp2, lg);
  k_softmax<<<1, 1024, 0, stream>>>(lg, out);
}

// Round 4
// 360.878 us; speedup vs baseline: 1.1973x; 1.0990x over previous
//
#include <hip/hip_runtime.h>
#include <math.h>

#define N_NODES 10000
#define N_EDGES 320000
#define N_AUG   (N_EDGES + N_NODES)
#define HID     256

// ---------------- degree + edge_attr segment sum ----------------
__global__ void k_deg(const int* __restrict__ dst, const float* __restrict__ ea,
                      int* __restrict__ deg, float* __restrict__ asum) {
  int e = blockIdx.x * blockDim.x + threadIdx.x;
  if (e < N_EDGES) {
    int d = dst[e];
    atomicAdd(&deg[d], 1);
    atomicAdd(&asum[d], ea[e]);
  }
}

// ------- exclusive scan of (deg+1) over 10000 nodes (parallel), + loop_attr --
__global__ void __launch_bounds__(256) k_scan(
    const int* __restrict__ deg, const float* __restrict__ asum,
    int* __restrict__ offs, float* __restrict__ lattr) {
  __shared__ int wsum[4];
  int t = threadIdx.x;
  int base = t * 40;
  int s = 0;
  for (int i = 0; i < 40; i++) {
    int n = base + i;
    if (n < N_NODES) s += deg[n] + 1;
  }
  int v = s;
  #pragma unroll
  for (int d = 1; d < 64; d <<= 1) {
    int u = __shfl_up(v, d);
    if ((t & 63) >= d) v += u;
  }
  if ((t & 63) == 63) wsum[t >> 6] = v;
  __syncthreads();
  int wb = 0;
  for (int i = 0; i < (t >> 6); i++) wb += wsum[i];
  int run = wb + v - s;
  for (int i = 0; i < 40; i++) {
    int n = base + i;
    if (n < N_NODES) {
      offs[n] = run;
      int d = deg[n];
      run += d + 1;
      lattr[n] = asum[n] / (float)max(d, 1);
    }
  }
  if (t == 255) offs[N_NODES] = wb + v;
}

// ------- scatter edges (incl. self loops) into CSR by dst, packed (src,ea) --
__global__ void k_scatter(const int* __restrict__ src, const int* __restrict__ dst,
                          const float* __restrict__ ea, const float* __restrict__ lattr,
                          const int* __restrict__ offs, int* __restrict__ cursor,
                          int2* __restrict__ cpk) {
  int e = blockIdx.x * blockDim.x + threadIdx.x;
  if (e >= N_AUG) return;
  int s, d; float a;
  if (e < N_EDGES) { s = src[e]; d = dst[e]; a = ea[e]; }
  else             { s = e - N_EDGES; d = s; a = lattr[s]; }
  int pos = offs[d] + atomicAdd(&cursor[d], 1);
  cpk[pos] = make_int2(s, __float_as_int(a));
}

// ---------------- conv1: fully fused (xform recomputed per edge from x) -----
// One wave per dst node; lane owns channels 4l..4l+3. IN=4 -> xl[s] row is
// recomputed from a wave-uniform s_load of x[s] (16B) + per-lane W columns.
// No online max (logits O(+-10)); 2-edge unroll.
__global__ void __launch_bounds__(256) k_conv1(
    const float* __restrict__ x,
    const float* __restrict__ Wl, const float* __restrict__ bl,
    const float* __restrict__ Wr, const float* __restrict__ br,
    const float* __restrict__ We, const float* __restrict__ att,
    const int* __restrict__ offs, const int2* __restrict__ cpk,
    const float* __restrict__ bias, const float* __restrict__ g,
    const float* __restrict__ be, float* __restrict__ hout) {
  int t = threadIdx.x;
  int n = blockIdx.x * 4 + (t >> 6);
  int c = 4 * (t & 63);

  float4 wl0 = *(const float4*)&Wl[0*HID + c];
  float4 wl1 = *(const float4*)&Wl[1*HID + c];
  float4 wl2 = *(const float4*)&Wl[2*HID + c];
  float4 wl3 = *(const float4*)&Wl[3*HID + c];
  float4 blv = *(const float4*)&bl[c];
  float4 we  = *(const float4*)&We[c];
  float4 at  = *(const float4*)&att[c];

  // xr row for this dst node, computed once
  float4 xn = *(const float4*)&x[n*4];
  float4 r4;
  {
    float4 wr0 = *(const float4*)&Wr[0*HID + c];
    float4 wr1 = *(const float4*)&Wr[1*HID + c];
    float4 wr2 = *(const float4*)&Wr[2*HID + c];
    float4 wr3 = *(const float4*)&Wr[3*HID + c];
    float4 brv = *(const float4*)&br[c];
    r4.x = fmaf(xn.x,wr0.x, fmaf(xn.y,wr1.x, fmaf(xn.z,wr2.x, fmaf(xn.w,wr3.x, brv.x))));
    r4.y = fmaf(xn.x,wr0.y, fmaf(xn.y,wr1.y, fmaf(xn.z,wr2.y, fmaf(xn.w,wr3.y, brv.y))));
    r4.z = fmaf(xn.x,wr0.z, fmaf(xn.y,wr1.z, fmaf(xn.z,wr2.z, fmaf(xn.w,wr3.z, brv.z))));
    r4.w = fmaf(xn.x,wr0.w, fmaf(xn.y,wr1.w, fmaf(xn.z,wr2.w, fmaf(xn.w,wr3.w, brv.w))));
  }

  int js = __builtin_amdgcn_readfirstlane(offs[n]);
  int je = __builtin_amdgcn_readfirstlane(offs[n+1]);

  float D = 0.f, a0 = 0.f, a1 = 0.f, a2 = 0.f, a3 = 0.f;

  int j = js;
  for (; j + 1 < je; j += 2) {
    int2 eA = cpk[j], eB = cpk[j+1];
    int sA = __builtin_amdgcn_readfirstlane(eA.x);
    int sB = __builtin_amdgcn_readfirstlane(eB.x);
    float avA = __int_as_float(eA.y), avB = __int_as_float(eB.y);
    float4 xA = *(const float4*)&x[sA*4];   // wave-uniform -> s_load
    float4 xB = *(const float4*)&x[sB*4];

    // edge A
    float l0 = fmaf(xA.x,wl0.x, fmaf(xA.y,wl1.x, fmaf(xA.z,wl2.x, fmaf(xA.w,wl3.x, blv.x))));
    float l1 = fmaf(xA.x,wl0.y, fmaf(xA.y,wl1.y, fmaf(xA.z,wl2.y, fmaf(xA.w,wl3.y, blv.y))));
    float l2 = fmaf(xA.x,wl0.z, fmaf(xA.y,wl1.z, fmaf(xA.z,wl2.z, fmaf(xA.w,wl3.z, blv.z))));
    float l3 = fmaf(xA.x,wl0.w, fmaf(xA.y,wl1.w, fmaf(xA.z,wl2.w, fmaf(xA.w,wl3.w, blv.w))));
    float m0 = l0 + fmaf(avA, we.x, r4.x); m0 = fmaxf(m0, 0.2f*m0);
    float m1 = l1 + fmaf(avA, we.y, r4.y); m1 = fmaxf(m1, 0.2f*m1);
    float m2 = l2 + fmaf(avA, we.z, r4.z); m2 = fmaxf(m2, 0.2f*m2);
    float m3 = l3 + fmaf(avA, we.w, r4.w); m3 = fmaxf(m3, 0.2f*m3);
    float pA = m0*at.x + m1*at.y + m2*at.z + m3*at.w;

    // edge B
    float k0 = fmaf(xB.x,wl0.x, fmaf(xB.y,wl1.x, fmaf(xB.z,wl2.x, fmaf(xB.w,wl3.x, blv.x))));
    float k1 = fmaf(xB.x,wl0.y, fmaf(xB.y,wl1.y, fmaf(xB.z,wl2.y, fmaf(xB.w,wl3.y, blv.y))));
    float k2 = fmaf(xB.x,wl0.z, fmaf(xB.y,wl1.z, fmaf(xB.z,wl2.z, fmaf(xB.w,wl3.z, blv.z))));
    float k3 = fmaf(xB.x,wl0.w, fmaf(xB.y,wl1.w, fmaf(xB.z,wl2.w, fmaf(xB.w,wl3.w, blv.w))));
    float q0 = k0 + fmaf(avB, we.x, r4.x); q0 = fmaxf(q0, 0.2f*q0);
    float q1 = k1 + fmaf(avB, we.y, r4.y); q1 = fmaxf(q1, 0.2f*q1);
    float q2 = k2 + fmaf(avB, we.z, r4.z); q2 = fmaxf(q2, 0.2f*q2);
    float q3 = k3 + fmaf(avB, we.w, r4.w); q3 = fmaxf(q3, 0.2f*q3);
    float pB = q0*at.x + q1*at.y + q2*at.z + q3*at.w;

    #pragma unroll
    for (int msk = 1; msk < 16; msk <<= 1) {
      pA += __shfl_xor(pA, msk);
      pB += __shfl_xor(pB, msk);
    }
    float eAx = expf(pA), eBx = expf(pB);
    D += eAx + eBx;
    a0 = fmaf(eBx, k0, fmaf(eAx, l0, a0));
    a1 = fmaf(eBx, k1, fmaf(eAx, l1, a1));
    a2 = fmaf(eBx, k2, fmaf(eAx, l2, a2));
    a3 = fmaf(eBx, k3, fmaf(eAx, l3, a3));
  }
  if (j < je) {
    int2 eA = cpk[j];
    int sA = __builtin_amdgcn_readfirstlane(eA.x);
    float avA = __int_as_float(eA.y);
    float4 xA = *(const float4*)&x[sA*4];
    float l0 = fmaf(xA.x,wl0.x, fmaf(xA.y,wl1.x, fmaf(xA.z,wl2.x, fmaf(xA.w,wl3.x, blv.x))));
    float l1 = fmaf(xA.x,wl0.y, fmaf(xA.y,wl1.y, fmaf(xA.z,wl2.y, fmaf(xA.w,wl3.y, blv.y))));
    float l2 = fmaf(xA.x,wl0.z, fmaf(xA.y,wl1.z, fmaf(xA.z,wl2.z, fmaf(xA.w,wl3.z, blv.z))));
    float l3 = fmaf(xA.x,wl0.w, fmaf(xA.y,wl1.w, fmaf(xA.z,wl2.w, fmaf(xA.w,wl3.w, blv.w))));
    float m0 = l0 + fmaf(avA, we.x, r4.x); m0 = fmaxf(m0, 0.2f*m0);
    float m1 = l1 + fmaf(avA, we.y, r4.y); m1 = fmaxf(m1, 0.2f*m1);
    float m2 = l2 + fmaf(avA, we.z, r4.z); m2 = fmaxf(m2, 0.2f*m2);
    float m3 = l3 + fmaf(avA, we.w, r4.w); m3 = fmaxf(m3, 0.2f*m3);
    float pA = m0*at.x + m1*at.y + m2*at.z + m3*at.w;
    #pragma unroll
    for (int msk = 1; msk < 16; msk <<= 1) pA += __shfl_xor(pA, msk);
    float eAx = expf(pA);
    D += eAx;
    a0 = fmaf(eAx, l0, a0);
    a1 = fmaf(eAx, l1, a1);
    a2 = fmaf(eAx, l2, a2);
    a3 = fmaf(eAx, l3, a3);
  }

  float inv = 1.f / D;
  float4 b4 = *(const float4*)&bias[c];
  float o0 = fmaf(a0, inv, b4.x);
  float o1 = fmaf(a1, inv, b4.y);
  float o2 = fmaf(a2, inv, b4.z);
  float o3 = fmaf(a3, inv, b4.w);

  float s = o0 + o1 + o2 + o3;
  #pragma unroll
  for (int msk = 1; msk < 64; msk <<= 1) s += __shfl_xor(s, msk);
  float mu = s * (1.f / 256.f);
  float d0 = o0 - mu, d1 = o1 - mu, d2 = o2 - mu, d3 = o3 - mu;
  float sq = d0*d0 + d1*d1 + d2*d2 + d3*d3;
  #pragma unroll
  for (int msk = 1; msk < 64; msk <<= 1) sq += __shfl_xor(sq, msk);
  float rstd = rsqrtf(sq * (1.f / 256.f) + 1e-5f);
  float4 g4  = *(const float4*)&g[c];
  float4 be4 = *(const float4*)&be[c];
  float4 o;
  o.x = fmaxf(fmaf(d0 * rstd, g4.x, be4.x), 0.f);
  o.y = fmaxf(fmaf(d1 * rstd, g4.y, be4.y), 0.f);
  o.z = fmaxf(fmaf(d2 * rstd, g4.z, be4.z), 0.f);
  o.w = fmaxf(fmaf(d3 * rstd, g4.w, be4.w), 0.f);
  *(float4*)&hout[n*HID + c] = o;
}

// ---------------- conv2: gather-based, no online max, 4-edge unroll ---------
__global__ void __launch_bounds__(256) k_conv2(
    const float* __restrict__ xl, const float* __restrict__ xr,
    const int* __restrict__ offs, const int2* __restrict__ cpk,
    const float* __restrict__ We, const float* __restrict__ att,
    const float* __restrict__ bias, const float* __restrict__ g,
    const float* __restrict__ be, float* __restrict__ hout) {
  int t = threadIdx.x;
  int n = blockIdx.x * 4 + (t >> 6);
  int c = 4 * (t & 63);
  float4 r4 = *(const float4*)&xr[n*HID + c];
  float4 we = *(const float4*)&We[c];
  float4 at = *(const float4*)&att[c];
  int js = __builtin_amdgcn_readfirstlane(offs[n]);
  int je = __builtin_amdgcn_readfirstlane(offs[n+1]);

  float D = 0.f, a0 = 0.f, a1 = 0.f, a2 = 0.f, a3 = 0.f;

  int j = js;
  for (; j + 3 < je; j += 4) {
    int2 e0 = cpk[j], e1 = cpk[j+1], e2 = cpk[j+2], e3 = cpk[j+3];
    float av0 = __int_as_float(e0.y), av1 = __int_as_float(e1.y);
    float av2 = __int_as_float(e2.y), av3 = __int_as_float(e3.y);
    float4 xs0 = *(const float4*)&xl[e0.x*HID + c];
    float4 xs1 = *(const float4*)&xl[e1.x*HID + c];
    float4 xs2 = *(const float4*)&xl[e2.x*HID + c];
    float4 xs3 = *(const float4*)&xl[e3.x*HID + c];

    float p0, p1, p2, p3;
    {
      float m0 = xs0.x + fmaf(av0, we.x, r4.x); m0 = fmaxf(m0, 0.2f*m0);
      float m1 = xs0.y + fmaf(av0, we.y, r4.y); m1 = fmaxf(m1, 0.2f*m1);
      float m2 = xs0.z + fmaf(av0, we.z, r4.z); m2 = fmaxf(m2, 0.2f*m2);
      float m3 = xs0.w + fmaf(av0, we.w, r4.w); m3 = fmaxf(m3, 0.2f*m3);
      p0 = m0*at.x + m1*at.y + m2*at.z + m3*at.w;
    }
    {
      float m0 = xs1.x + fmaf(av1, we.x, r4.x); m0 = fmaxf(m0, 0.2f*m0);
      float m1 = xs1.y + fmaf(av1, we.y, r4.y); m1 = fmaxf(m1, 0.2f*m1);
      float m2 = xs1.z + fmaf(av1, we.z, r4.z); m2 = fmaxf(m2, 0.2f*m2);
      float m3 = xs1.w + fmaf(av1, we.w, r4.w); m3 = fmaxf(m3, 0.2f*m3);
      p1 = m0*at.x + m1*at.y + m2*at.z + m3*at.w;
    }
    {
      float m0 = xs2.x + fmaf(av2, we.x, r4.x); m0 = fmaxf(m0, 0.2f*m0);
      float m1 = xs2.y + fmaf(av2, we.y, r4.y); m1 = fmaxf(m1, 0.2f*m1);
      float m2 = xs2.z + fmaf(av2, we.z, r4.z); m2 = fmaxf(m2, 0.2f*m2);
      float m3 = xs2.w + fmaf(av2, we.w, r4.w); m3 = fmaxf(m3, 0.2f*m3);
      p2 = m0*at.x + m1*at.y + m2*at.z + m3*at.w;
    }
    {
      float m0 = xs3.x + fmaf(av3, we.x, r4.x); m0 = fmaxf(m0, 0.2f*m0);
      float m1 = xs3.y + fmaf(av3, we.y, r4.y); m1 = fmaxf(m1, 0.2f*m1);
      float m2 = xs3.z + fmaf(av3, we.z, r4.z); m2 = fmaxf(m2, 0.2f*m2);
      float m3 = xs3.w + fmaf(av3, we.w, r4.w); m3 = fmaxf(m3, 0.2f*m3);
      p3 = m0*at.x + m1*at.y + m2*at.z + m3*at.w;
    }
    #pragma unroll
    for (int msk = 1; msk < 64; msk <<= 1) {
      p0 += __shfl_xor(p0, msk);
      p1 += __shfl_xor(p1, msk);
      p2 += __shfl_xor(p2, msk);
      p3 += __shfl_xor(p3, msk);
    }
    float x0 = expf(p0), x1 = expf(p1), x2 = expf(p2), x3 = expf(p3);
    D += (x0 + x1) + (x2 + x3);
    a0 = fmaf(x3, xs3.x, fmaf(x2, xs2.x, fmaf(x1, xs1.x, fmaf(x0, xs0.x, a0))));
    a1 = fmaf(x3, xs3.y, fmaf(x2, xs2.y, fmaf(x1, xs1.y, fmaf(x0, xs0.y, a1))));
    a2 = fmaf(x3, xs3.z, fmaf(x2, xs2.z, fmaf(x1, xs1.z, fmaf(x0, xs0.z, a2))));
    a3 = fmaf(x3, xs3.w, fmaf(x2, xs2.w, fmaf(x1, xs1.w, fmaf(x0, xs0.w, a3))));
  }
  for (; j < je; j++) {
    int2 e0 = cpk[j];
    float av0 = __int_as_float(e0.y);
    float4 xs0 = *(const float4*)&xl[e0.x*HID + c];
    float m0 = xs0.x + fmaf(av0, we.x, r4.x); m0 = fmaxf(m0, 0.2f*m0);
    float m1 = xs0.y + fmaf(av0, we.y, r4.y); m1 = fmaxf(m1, 0.2f*m1);
    float m2 = xs0.z + fmaf(av0, we.z, r4.z); m2 = fmaxf(m2, 0.2f*m2);
    float m3 = xs0.w + fmaf(av0, we.w, r4.w); m3 = fmaxf(m3, 0.2f*m3);
    float p0 = m0*at.x + m1*at.y + m2*at.z + m3*at.w;
    #pragma unroll
    for (int msk = 1; msk < 64; msk <<= 1) p0 += __shfl_xor(p0, msk);
    float x0 = expf(p0);
    D += x0;
    a0 = fmaf(x0, xs0.x, a0);
    a1 = fmaf(x0, xs0.y, a1);
    a2 = fmaf(x0, xs0.z, a2);
    a3 = fmaf(x0, xs0.w, a3);
  }

  float inv = 1.f / D;
  float4 b4 = *(const float4*)&bias[c];
  float o0 = fmaf(a0, inv, b4.x);
  float o1 = fmaf(a1, inv, b4.y);
  float o2 = fmaf(a2, inv, b4.z);
  float o3 = fmaf(a3, inv, b4.w);

  float s = o0 + o1 + o2 + o3;
  #pragma unroll
  for (int msk = 1; msk < 64; msk <<= 1) s += __shfl_xor(s, msk);
  float mu = s * (1.f / 256.f);
  float d0 = o0 - mu, d1 = o1 - mu, d2 = o2 - mu, d3 = o3 - mu;
  float sq = d0*d0 + d1*d1 + d2*d2 + d3*d3;
  #pragma unroll
  for (int msk = 1; msk < 64; msk <<= 1) sq += __shfl_xor(sq, msk);
  float rstd = rsqrtf(sq * (1.f / 256.f) + 1e-5f);
  float4 g4  = *(const float4*)&g[c];
  float4 be4 = *(const float4*)&be[c];
  float4 o;
  o.x = fmaxf(fmaf(d0 * rstd, g4.x, be4.x), 0.f);
  o.y = fmaxf(fmaf(d1 * rstd, g4.y, be4.y), 0.f);
  o.z = fmaxf(fmaf(d2 * rstd, g4.z, be4.z), 0.f);
  o.w = fmaxf(fmaf(d3 * rstd, g4.w, be4.w), 0.f);
  *(float4*)&hout[n*HID + c] = o;
}

// ---------------- dual GEMM: O1 = A@W1+b1, O2 = A@W2+b2  (A: 10000x256) -----
__global__ void __launch_bounds__(256) k_gemm_dual(
    const float* __restrict__ A,
    const float* __restrict__ W1, const float* __restrict__ b1,
    const float* __restrict__ W2, const float* __restrict__ b2,
    float* __restrict__ O1, float* __restrict__ O2) {
  __shared__ float As[16][64];
  __shared__ float Ws1[16][64];
  __shared__ float Ws2[16][64];
  int t = threadIdx.x;
  int r0 = blockIdx.x * 64;
  int c0 = blockIdx.y * 64;
  int tx = t & 15, ty = t >> 4;

  float acc1[4][4] = {{0}};
  float acc2[4][4] = {{0}};

  int ar = t >> 2;
  int ak = (t & 3) * 4;
  int arow = min(r0 + ar, N_NODES - 1);
  int wk = t >> 4;
  int wc = (t & 15) * 4;

  for (int k0 = 0; k0 < HID; k0 += 16) {
    float4 av  = *(const float4*)&A [arow*HID + k0 + ak];
    float4 w1v = *(const float4*)&W1[(k0+wk)*HID + c0 + wc];
    float4 w2v = *(const float4*)&W2[(k0+wk)*HID + c0 + wc];
    __syncthreads();
    As[ak+0][ar] = av.x; As[ak+1][ar] = av.y;
    As[ak+2][ar] = av.z; As[ak+3][ar] = av.w;
    *(float4*)&Ws1[wk][wc] = w1v;
    *(float4*)&Ws2[wk][wc] = w2v;
    __syncthreads();
    #pragma unroll
    for (int k = 0; k < 16; k++) {
      float4 a4  = *(const float4*)&As [k][4*ty];
      float4 w14 = *(const float4*)&Ws1[k][4*tx];
      float4 w24 = *(const float4*)&Ws2[k][4*tx];
      const float aa[4] = {a4.x, a4.y, a4.z, a4.w};
      const float ww1[4] = {w14.x, w14.y, w14.z, w14.w};
      const float ww2[4] = {w24.x, w24.y, w24.z, w24.w};
      #pragma unroll
      for (int i = 0; i < 4; i++)
        #pragma unroll
        for (int jj = 0; jj < 4; jj++) {
          acc1[i][jj] = fmaf(aa[i], ww1[jj], acc1[i][jj]);
          acc2[i][jj] = fmaf(aa[i], ww2[jj], acc2[i][jj]);
        }
    }
  }
  int cbase = c0 + 4*tx;
  float4 b1v = *(const float4*)&b1[cbase];
  float4 b2v = *(const float4*)&b2[cbase];
  #pragma unroll
  for (int i = 0; i < 4; i++) {
    int r = r0 + 4*ty + i;
    if (r < N_NODES) {
      float4 o1 = {acc1[i][0]+b1v.x, acc1[i][1]+b1v.y, acc1[i][2]+b1v.z, acc1[i][3]+b1v.w};
      float4 o2 = {acc2[i][0]+b2v.x, acc2[i][1]+b2v.y, acc2[i][2]+b2v.z, acc2[i][3]+b2v.w};
      *(float4*)&O1[r*HID + cbase] = o1;
      *(float4*)&O2[r*HID + cbase] = o2;
    }
  }
}

// ------- fused policy head: e=exp(relu(h@Wp1+bp1)@Wp2+bp2), partial sums ----
__global__ void __launch_bounds__(256) k_policy(
    const float* __restrict__ h,
    const float* __restrict__ Wp1, const float* __restrict__ bp1,
    const float* __restrict__ Wp2, const float* __restrict__ bp2,
    float* __restrict__ elg, float* __restrict__ tot) {
  __shared__ float As[16][64];
  __shared__ float Ws[16][128];
  __shared__ float hidl[64][132];
  __shared__ float wred[4];
  int t = threadIdx.x;
  int r0 = blockIdx.x * 64;
  int tx = t & 15, ty = t >> 4;

  float acc[4][8] = {{0}};

  int ar = t >> 2;
  int ak = (t & 3) * 4;
  int arow = min(r0 + ar, N_NODES - 1);
  int wk = t >> 4;
  int wc = (t & 15) * 8;

  for (int k0 = 0; k0 < HID; k0 += 16) {
    float4 av  = *(const float4*)&h[arow*HID + k0 + ak];
    float4 wva = *(const float4*)&Wp1[(k0+wk)*128 + wc];
    float4 wvb = *(const float4*)&Wp1[(k0+wk)*128 + wc + 4];
    __syncthreads();
    As[ak+0][ar] = av.x; As[ak+1][ar] = av.y;
    As[ak+2][ar] = av.z; As[ak+3][ar] = av.w;
    *(float4*)&Ws[wk][wc]     = wva;
    *(float4*)&Ws[wk][wc + 4] = wvb;
    __syncthreads();
    #pragma unroll
    for (int k = 0; k < 16; k++) {
      float4 a4 = *(const float4*)&As[k][4*ty];
      float4 wA = *(const float4*)&Ws[k][8*tx];
      float4 wB = *(const float4*)&Ws[k][8*tx + 4];
      const float aa[4] = {a4.x, a4.y, a4.z, a4.w};
      const float ww[8] = {wA.x, wA.y, wA.z, wA.w, wB.x, wB.y, wB.z, wB.w};
      #pragma unroll
      for (int i = 0; i < 4; i++)
        #pragma unroll
        for (int jj = 0; jj < 8; jj++)
          acc[i][jj] = fmaf(aa[i], ww[jj], acc[i][jj]);
    }
  }
  int cbase = 8*tx;
  float4 bA = *(const float4*)&bp1[cbase];
  float4 bB = *(const float4*)&bp1[cbase + 4];
  const float bb[8] = {bA.x, bA.y, bA.z, bA.w, bB.x, bB.y, bB.z, bB.w};
  #pragma unroll
  for (int i = 0; i < 4; i++) {
    int r = 4*ty + i;
    float4 oA = {fmaxf(acc[i][0]+bb[0],0.f), fmaxf(acc[i][1]+bb[1],0.f),
                 fmaxf(acc[i][2]+bb[2],0.f), fmaxf(acc[i][3]+bb[3],0.f)};
    float4 oB = {fmaxf(acc[i][4]+bb[4],0.f), fmaxf(acc[i][5]+bb[5],0.f),
                 fmaxf(acc[i][6]+bb[6],0.f), fmaxf(acc[i][7]+bb[7],0.f)};
    *(float4*)&hidl[r][cbase]     = oA;
    *(float4*)&hidl[r][cbase + 4] = oB;
  }
  __syncthreads();
  int nl = t >> 2, i = t & 3;
  float s = bp2[i];
  for (int k = 0; k < 128; k += 4) {
    float4 hv = *(const float4*)&hidl[nl][k];
    s = fmaf(hv.x, Wp2[(k+0)*4 + i],
        fmaf(hv.y, Wp2[(k+1)*4 + i],
        fmaf(hv.z, Wp2[(k+2)*4 + i],
        fmaf(hv.w, Wp2[(k+3)*4 + i], s))));
  }
  int n = r0 + nl;
  float e = 0.f;
  if (n < N_NODES) {
    e = expf(s);
    elg[n*4 + i] = e;
  }
  // block reduce of e -> one atomic
  float r = e;
  #pragma unroll
  for (int msk = 1; msk < 64; msk <<= 1) r += __shfl_xor(r, msk);
  if ((t & 63) == 0) wred[t >> 6] = r;
  __syncthreads();
  if (t == 0) atomicAdd(tot, (wred[0] + wred[1]) + (wred[2] + wred[3]));
}

// ---------------- normalize: out = elg * (1/tot) ----------------------------
__global__ void __launch_bounds__(1024) k_sm_final(const float* __restrict__ elg,
                                                   const float* __restrict__ tot,
                                                   float* __restrict__ out) {
  int i = blockIdx.x * 1024 + threadIdx.x;
  float inv = 1.f / tot[0];
  if (i < N_NODES * 4) out[i] = elg[i] * inv;
}

extern "C" void kernel_launch(void* const* d_in, const int* in_sizes, int n_in,
                              void* d_out, int out_size, void* d_ws, size_t ws_size,
                              hipStream_t stream) {
  const float* x    = (const float*)d_in[0];
  const int*   ei   = (const int*)  d_in[1];
  const float* ea   = (const float*)d_in[2];
  const float* Wl1  = (const float*)d_in[3];
  const float* bl1  = (const float*)d_in[4];
  const float* Wr1  = (const float*)d_in[5];
  const float* br1  = (const float*)d_in[6];
  const float* We1  = (const float*)d_in[7];
  const float* att1 = (const float*)d_in[8];
  const float* bias1= (const float*)d_in[9];
  const float* g1   = (const float*)d_in[10];
  const float* be1  = (const float*)d_in[11];
  const float* Wl2  = (const float*)d_in[12];
  const float* bl2  = (const float*)d_in[13];
  const float* Wr2  = (const float*)d_in[14];
  const float* br2  = (const float*)d_in[15];
  const float* We2  = (const float*)d_in[16];
  const float* att2 = (const float*)d_in[17];
  const float* bias2= (const float*)d_in[18];
  const float* g2   = (const float*)d_in[19];
  const float* be2  = (const float*)d_in[20];
  const float* Wp1  = (const float*)d_in[21];
  const float* bp1  = (const float*)d_in[22];
  const float* Wp2  = (const float*)d_in[23];
  const float* bp2  = (const float*)d_in[24];
  float* out = (float*)d_out;

  const int* srcp = ei;
  const int* dstp = ei + N_EDGES;

  // workspace layout: [deg | cursor | asum | tot] zeroed in ONE memset
  int*   deg    = (int*)d_ws;               // 10240
  int*   cursor = deg + 10240;              // 10240
  float* asum   = (float*)(cursor + 10240); // 10240
  float* tot    = asum + 10240;             // 16
  int*   offs   = (int*)(tot + 16);         // 10240
  float* lattr  = (float*)(offs + 10240);   // 10240
  int2*  cpk    = (int2*)(lattr + 10240);   // N_AUG (+pad) int2
  float* h1     = (float*)(cpk + 330752);   // 2560000
  float* xl2    = h1 + 2560000;             // 2560000
  float* xr2    = xl2 + 2560000;            // 2560000
  float* elg    = xr2 + 2560000;            // 40960
  float* h2     = h1;                       // h1 dead after gemm

  hipMemsetAsync(deg, 0, (3 * 10240 + 16) * sizeof(int), stream);

  k_deg    <<<(N_EDGES + 255)/256, 256, 0, stream>>>(dstp, ea, deg, asum);
  k_scan   <<<1, 256, 0, stream>>>(deg, asum, offs, lattr);
  k_scatter<<<(N_AUG + 255)/256, 256, 0, stream>>>(srcp, dstp, ea, lattr, offs,
                                                   cursor, cpk);
  k_conv1  <<<N_NODES/4, 256, 0, stream>>>(x, Wl1, bl1, Wr1, br1, We1, att1,
                                           offs, cpk, bias1, g1, be1, h1);
  k_gemm_dual<<<dim3(157, 4), 256, 0, stream>>>(h1, Wl2, bl2, Wr2, br2, xl2, xr2);
  k_conv2  <<<N_NODES/4, 256, 0, stream>>>(xl2, xr2, offs, cpk,
                                           We2, att2, bias2, g2, be2, h2);
  k_policy <<<157, 256, 0, stream>>>(h2, Wp1, bp1, Wp2, bp2, elg, tot);
  k_sm_final<<<40, 1024, 0, stream>>>(elg, tot, out);
}